// Round 2
// baseline (68.246 us; speedup 1.0000x reference)
//
#include <hip/hip_runtime.h>

// Problem dims (fixed by reference)
constexpr int T = 64, B = 8, A = 3, S = 400, V = 50000, N_OOV = 400;
constexpr int V_EXT = V + N_OOV;

constexpr int NSUB   = 4;             // sub-blocks per (t,b) region
constexpr int C4     = V_EXT / 4;     // 12600 float4 per (t,b)
constexpr int C4_SUB = C4 / NSUB;     // 3150 float4 per block
constexpr int V4     = V / 4;         // 12500 float4 of base vocab

// Kernel 1: barrier-free scaled stream. out[v<V] = coef*vp[v]; out[V:]=0.
// 2048 blocks x 256 thr = 32 waves/CU; 12 unrolled iterations per thread.
__global__ __launch_bounds__(256) void stream_kernel(
    const float* __restrict__ vocab_probs,    // [T,B,V]
    const float* __restrict__ gen_probs,      // [T,B,A]
    const float* __restrict__ agent_attn,     // [T,B,A]
    float*       __restrict__ out)            // [T,B,V_EXT]
{
    const int bid = blockIdx.x;
    const int tb  = bid >> 2;       // bid / NSUB
    const int sub = bid & 3;        // bid % NSUB
    const int tid = threadIdx.x;

    float coef = 0.f;
#pragma unroll
    for (int a = 0; a < A; ++a)
        coef += agent_attn[tb * A + a] * gen_probs[tb * A + a];

    const float4* vp4  = reinterpret_cast<const float4*>(vocab_probs + (size_t)tb * V);
    float4*       out4 = reinterpret_cast<float4*>(out + (size_t)tb * V_EXT);

    const int base = sub * C4_SUB;
    int i = base + tid;
#pragma unroll 4
    for (int k = 0; k < 12; ++k, i += 256) {   // 12*256 = 3072 of 3150
        float4 r;
        if (i < V4) {
            r = vp4[i];
            r.x *= coef; r.y *= coef; r.z *= coef; r.w *= coef;
        } else {
            r = make_float4(0.f, 0.f, 0.f, 0.f);
        }
        out4[i] = r;
    }
    if (i < base + C4_SUB) {                   // tail: 78 chunks
        float4 r;
        if (i < V4) {
            r = vp4[i];
            r.x *= coef; r.y *= coef; r.z *= coef; r.w *= coef;
        } else {
            r = make_float4(0.f, 0.f, 0.f, 0.f);
        }
        out4[i] = r;
    }
}

// Kernel 2: sparse scatter. 1200 atomics per (t,b), lines L2-hot from kernel 1.
__global__ __launch_bounds__(256) void scatter_kernel(
    const int*   __restrict__ article,        // [S,B,A]
    const float* __restrict__ gen_probs,      // [T,B,A]
    const float* __restrict__ agentwise_attn, // [T,B,A,S]
    const float* __restrict__ agent_attn,     // [T,B,A]
    float*       __restrict__ out)            // [T,B,V_EXT]
{
    const int tb  = blockIdx.x;               // t*B + b
    const int b   = tb % B;
    const int tid = threadIdx.x;

    float cw[A];
#pragma unroll
    for (int a = 0; a < A; ++a)
        cw[a] = agent_attn[tb * A + a] * (1.f - gen_probs[tb * A + a]);

    float* outp = out + (size_t)tb * V_EXT;
    for (int i = tid; i < A * S; i += 256) {
        const int a = i / S;
        const int s = i - a * S;
        const float w   = cw[a] * agentwise_attn[((size_t)tb * A + a) * S + s];
        const int   idx = article[(s * B + b) * A + a];
        atomicAdd(outp + idx, w);
    }
}

extern "C" void kernel_launch(void* const* d_in, const int* in_sizes, int n_in,
                              void* d_out, int out_size, void* d_ws, size_t ws_size,
                              hipStream_t stream) {
    const int*   article        = (const int*)  d_in[0]; // [S,B,A]
    const float* vocab_probs    = (const float*)d_in[1]; // [T,B,V]
    const float* gen_probs      = (const float*)d_in[2]; // [T,B,A]
    const float* agentwise_attn = (const float*)d_in[3]; // [T,B,A,S]
    const float* agent_attn     = (const float*)d_in[4]; // [T,B,A]
    float*       out            = (float*)d_out;         // [T,B,V_EXT]

    stream_kernel<<<dim3(T * B * NSUB), dim3(256), 0, stream>>>(
        vocab_probs, gen_probs, agent_attn, out);
    scatter_kernel<<<dim3(T * B), dim3(256), 0, stream>>>(
        article, gen_probs, agentwise_attn, agent_attn, out);
}

// Round 3
// 51.013 us; speedup vs baseline: 1.3378x; 1.3378x over previous
//
#include <hip/hip_runtime.h>

// Problem dims (fixed by reference)
constexpr int T = 64, B = 8, A = 3, S = 400, V = 50000, N_OOV = 400;
constexpr int V_EXT = V + N_OOV;       // 50400
constexpr int NSUB   = 4;              // sub-blocks per (t,b) region
constexpr int C4     = V_EXT / 4;      // 12600 float4 per (t,b)
constexpr int C4_SUB = C4 / NSUB;      // 3150 float4 per block
constexpr int V4     = V / 4;          // 12500 float4 of base vocab
constexpr int NTHR   = 256;

// One block per (t,b,quarter). Phase 1: branchless scaled stream of the
// quarter (subs 0-2 are provably pure-vocab; only sub 3 mixes vocab+OOV-zero).
// Phase 2 (same block, after __syncthreads): scan all A*S=1200 scatter
// entries, apply only those whose idx lands in this block's own quarter.
// Atomics are ordered after this block's stores and stay L2-local.
__global__ __launch_bounds__(NTHR) void pg_fused_kernel(
    const int*   __restrict__ article,        // [S,B,A]
    const float* __restrict__ vocab_probs,    // [T,B,V]
    const float* __restrict__ gen_probs,      // [T,B,A]
    const float* __restrict__ agentwise_attn, // [T,B,A,S]
    const float* __restrict__ agent_attn,     // [T,B,A]
    float*       __restrict__ out)            // [T,B,V_EXT]
{
    const int bid = blockIdx.x;
    const int tb  = bid >> 2;        // (t*B + b)
    const int sub = bid & 3;
    const int b   = tb % B;
    const int tid = threadIdx.x;

    float coef = 0.f;
    float cw[A];
#pragma unroll
    for (int a = 0; a < A; ++a) {
        const float aa = agent_attn[tb * A + a];
        const float g  = gen_probs[tb * A + a];
        coef += aa * g;
        cw[a] = aa * (1.f - g);
    }

    const float4* vp4  = reinterpret_cast<const float4*>(vocab_probs + (size_t)tb * V);
    float4*       out4 = reinterpret_cast<float4*>(out + (size_t)tb * V_EXT);
    const int base = sub * C4_SUB;

    if (sub < 3) {
        // Pure-copy quarter: 3150 chunks = 12 full strides + 78-tail.
        // Fully unrolled branchless body -> 12 loads batched in flight.
        int i = base + tid;
#pragma unroll
        for (int k = 0; k < 12; ++k) {
            float4 r = vp4[i];
            r.x *= coef; r.y *= coef; r.z *= coef; r.w *= coef;
            out4[i] = r;
            i += NTHR;
        }
        if (i < base + C4_SUB) {
            float4 r = vp4[i];
            r.x *= coef; r.y *= coef; r.z *= coef; r.w *= coef;
            out4[i] = r;
        }
    } else {
        // Mixed quarter: vocab up to V4, zeros beyond (OOV slots).
        int i = base + tid;
#pragma unroll
        for (int k = 0; k < 12; ++k) {
            float4 r = make_float4(0.f, 0.f, 0.f, 0.f);
            if (i < V4) {
                r = vp4[i];
                r.x *= coef; r.y *= coef; r.z *= coef; r.w *= coef;
            }
            out4[i] = r;
            i += NTHR;
        }
        if (i < base + C4_SUB) {
            float4 r = make_float4(0.f, 0.f, 0.f, 0.f);
            if (i < V4) {
                r = vp4[i];
                r.x *= coef; r.y *= coef; r.z *= coef; r.w *= coef;
            }
            out4[i] = r;
        }
    }

    __syncthreads();   // this block's stores drained before its atomics

    // Scatter: filter the 1200 entries to this quarter's element range.
    const int lo = base * 4;
    const int hi = lo + C4_SUB * 4;
    float* outp = out + (size_t)tb * V_EXT;
    const float* aw = agentwise_attn + (size_t)tb * A * S;  // [a][s] flat == i2
    for (int i2 = tid; i2 < A * S; i2 += NTHR) {
        const int a   = i2 / S;
        const int s   = i2 - a * S;
        const int idx = article[(s * B + b) * A + a];
        if (idx >= lo && idx < hi) {
            atomicAdd(outp + idx, cw[a] * aw[i2]);
        }
    }
}

extern "C" void kernel_launch(void* const* d_in, const int* in_sizes, int n_in,
                              void* d_out, int out_size, void* d_ws, size_t ws_size,
                              hipStream_t stream) {
    const int*   article        = (const int*)  d_in[0]; // [S,B,A]
    const float* vocab_probs    = (const float*)d_in[1]; // [T,B,V]
    const float* gen_probs      = (const float*)d_in[2]; // [T,B,A]
    const float* agentwise_attn = (const float*)d_in[3]; // [T,B,A,S]
    const float* agent_attn     = (const float*)d_in[4]; // [T,B,A]
    float*       out            = (float*)d_out;         // [T,B,V_EXT]

    pg_fused_kernel<<<dim3(T * B * NSUB), dim3(NTHR), 0, stream>>>(
        article, vocab_probs, gen_probs, agentwise_attn, agent_attn, out);
}

// Round 4
// 39.683 us; speedup vs baseline: 1.7198x; 1.2855x over previous
//
#include <hip/hip_runtime.h>

// Problem dims (fixed by reference)
constexpr int T = 64, B = 8, A = 3, S = 400, V = 50000, N_OOV = 400;
constexpr int V_EXT  = V + N_OOV;      // 50400
constexpr int NSUB   = 4;              // quarter-slices per (t,b)
constexpr int C_SUB  = V_EXT / NSUB;   // 12600 floats per slice
constexpr int C4_SUB = C_SUB / 4;      // 3150 float4 per slice
constexpr int V4     = V / 4;          // 12500 float4 of base vocab
constexpr int NTHR   = 512;
constexpr int FULL_K = C4_SUB / NTHR;  // 6 full strides (+78 tail)

// One block per (t,b,quarter). LDS accumulator for the slice:
//   1) zero LDS
//   2) scatter copy-weights into LDS (LDS atomics; entries filtered to slice)
//   3) out[i] = coef*vp[i] (if in base vocab) + acc[i]  -- single write stream,
//      loads batched 6-deep in registers for memory-level parallelism.
// No global atomics, no global store->atomic ordering barrier.
__global__ __launch_bounds__(NTHR) void pg_lds_kernel(
    const int*   __restrict__ article,        // [S,B,A]
    const float* __restrict__ vocab_probs,    // [T,B,V]
    const float* __restrict__ gen_probs,      // [T,B,A]
    const float* __restrict__ agentwise_attn, // [T,B,A,S]
    const float* __restrict__ agent_attn,     // [T,B,A]
    float*       __restrict__ out)            // [T,B,V_EXT]
{
    __shared__ float acc[C_SUB];               // 50400 B
    const int bid = blockIdx.x;
    const int tb  = bid >> 2;                  // t*B + b
    const int sub = bid & 3;
    const int b   = tb % B;
    const int tid = threadIdx.x;

    // zero the slice accumulator (3150 float4 / 512 thr)
    float4* acc4 = reinterpret_cast<float4*>(acc);
    for (int j = tid; j < C4_SUB; j += NTHR)
        acc4[j] = make_float4(0.f, 0.f, 0.f, 0.f);

    float coef = 0.f;
    float cw[A];
#pragma unroll
    for (int a = 0; a < A; ++a) {
        const float aa = agent_attn[tb * A + a];
        const float g  = gen_probs[tb * A + a];
        coef += aa * g;
        cw[a] = aa * (1.f - g);
    }

    __syncthreads();

    // scatter: filter A*S=1200 entries to this slice, accumulate in LDS
    const int lo = sub * C_SUB;
    const int hi = lo + C_SUB;
    const float* aw = agentwise_attn + (size_t)tb * A * S;  // flat [a*S+s]
    for (int i2 = tid; i2 < A * S; i2 += NTHR) {
        const int a   = (i2 >= 2 * S) ? 2 : (i2 >= S ? 1 : 0);
        const int s   = i2 - a * S;
        const int idx = article[(s * B + b) * A + a];
        if (idx >= lo && idx < hi)
            atomicAdd(&acc[idx - lo], cw[a] * aw[i2]);
    }

    __syncthreads();

    // fused output stream with batched loads
    const float4* vp4  = reinterpret_cast<const float4*>(vocab_probs + (size_t)tb * V);
    float4*       out4 = reinterpret_cast<float4*>(out + (size_t)tb * V_EXT);
    const int base = sub * C4_SUB;
    const int i0   = base + tid;

    float4 v[FULL_K];
#pragma unroll
    for (int k = 0; k < FULL_K; ++k) {
        const int i  = i0 + k * NTHR;
        const int ic = (i < V4) ? i : (V4 - 1);   // clamp: harmless L3-hit load
        v[k] = vp4[ic];
    }
#pragma unroll
    for (int k = 0; k < FULL_K; ++k) {
        const int i = i0 + k * NTHR;
        float4 r = acc4[i - base];
        if (i < V4) {                              // uniform-true for sub<3
            r.x += coef * v[k].x;  r.y += coef * v[k].y;
            r.z += coef * v[k].z;  r.w += coef * v[k].w;
        }
        out4[i] = r;
    }
    // tail: 3150 - 6*512 = 78 chunks
    const int it = i0 + FULL_K * NTHR;
    if (it < base + C4_SUB) {
        float4 r = acc4[it - base];
        if (it < V4) {
            const float4 vv = vp4[it];
            r.x += coef * vv.x;  r.y += coef * vv.y;
            r.z += coef * vv.z;  r.w += coef * vv.w;
        }
        out4[it] = r;
    }
}

extern "C" void kernel_launch(void* const* d_in, const int* in_sizes, int n_in,
                              void* d_out, int out_size, void* d_ws, size_t ws_size,
                              hipStream_t stream) {
    const int*   article        = (const int*)  d_in[0]; // [S,B,A]
    const float* vocab_probs    = (const float*)d_in[1]; // [T,B,V]
    const float* gen_probs      = (const float*)d_in[2]; // [T,B,A]
    const float* agentwise_attn = (const float*)d_in[3]; // [T,B,A,S]
    const float* agent_attn     = (const float*)d_in[4]; // [T,B,A]
    float*       out            = (float*)d_out;         // [T,B,V_EXT]

    pg_lds_kernel<<<dim3(T * B * NSUB), dim3(NTHR), 0, stream>>>(
        article, vocab_probs, gen_probs, agentwise_attn, agent_attn, out);
}

// Round 5
// 37.864 us; speedup vs baseline: 1.8024x; 1.0480x over previous
//
#include <hip/hip_runtime.h>

// Problem dims (fixed by reference)
constexpr int T = 64, B = 8, A = 3, S = 400, V = 50000, N_OOV = 400;
constexpr int V_EXT  = V + N_OOV;      // 50400
constexpr int NSUB   = 6;              // slices per (t,b): 33.6 KB LDS -> 4 blocks/CU
constexpr int C_SUB  = V_EXT / NSUB;   // 8400 floats per slice
constexpr int C4_SUB = C_SUB / 4;      // 2100 float4 per slice
constexpr int V4     = V / 4;          // 12500 float4 of base vocab
constexpr int NTHR   = 512;
constexpr int FULL_K = C4_SUB / NTHR;  // 4 full strides (+52 tail)
constexpr int NSC    = 3;              // ceil(A*S / NTHR) scatter entries/thread

// One block per (t,b,slice). Pipeline by issue order:
//   1) load scatter entries (article idx + attn w) -- oldest vmcnt entries
//   2) issue ALL vocab_probs float4 prefetches (stay in flight)
//   3) zero LDS accumulator (no global mem)
//   4) scatter into LDS from registers (waits only on its own oldest loads)
//   5) combine acc + coef*vocab, single coalesced store stream
// Grid = 3072 = exactly 3.0 resident block-waves at 4 blocks/CU.
__global__ __launch_bounds__(NTHR, 8) void pg_pipe_kernel(
    const int*   __restrict__ article,        // [S,B,A]
    const float* __restrict__ vocab_probs,    // [T,B,V]
    const float* __restrict__ gen_probs,      // [T,B,A]
    const float* __restrict__ agentwise_attn, // [T,B,A,S]
    const float* __restrict__ agent_attn,     // [T,B,A]
    float*       __restrict__ out)            // [T,B,V_EXT]
{
    __shared__ float acc[C_SUB];               // 33600 B
    const int bid = blockIdx.x;
    const int tb  = bid / NSUB;                // t*B + b
    const int sub = bid - tb * NSUB;
    const int b   = tb % B;
    const int tid = threadIdx.x;

    // per-(t,b) scalars
    float coef = 0.f;
    float cw[A];
#pragma unroll
    for (int a = 0; a < A; ++a) {
        const float aa = agent_attn[tb * A + a];
        const float g  = gen_probs[tb * A + a];
        coef += aa * g;
        cw[a] = aa * (1.f - g);
    }

    // 1) scatter-entry loads first (oldest outstanding loads)
    int   sidx[NSC];
    float sraw[NSC];
    const float* aw = agentwise_attn + (size_t)tb * A * S;   // flat [a*S+s]
#pragma unroll
    for (int j = 0; j < NSC; ++j) {
        const int i2 = tid + j * NTHR;
        sidx[j] = -1; sraw[j] = 0.f;
        if (i2 < A * S) {
            const int a = (i2 >= 2 * S) ? 2 : (i2 >= S ? 1 : 0);
            const int s = i2 - a * S;
            sidx[j] = article[(s * B + b) * A + a];
            sraw[j] = aw[i2];
        }
    }

    // 2) issue vocab prefetches (in flight across the LDS phase)
    const float4* vp4  = reinterpret_cast<const float4*>(vocab_probs + (size_t)tb * V);
    float4*       out4 = reinterpret_cast<float4*>(out + (size_t)tb * V_EXT);
    const int base = sub * C4_SUB;
    const int i0   = base + tid;

    float4 v[FULL_K];
#pragma unroll
    for (int k = 0; k < FULL_K; ++k) {
        const int i  = i0 + k * NTHR;
        const int ic = (i < V4) ? i : (V4 - 1);   // clamp (only slice 5 mixes)
        v[k] = vp4[ic];
    }
    const int  it       = i0 + FULL_K * NTHR;
    const bool has_tail = (it < base + C4_SUB);   // 52 threads per block
    float4 vt = make_float4(0.f, 0.f, 0.f, 0.f);
    if (has_tail) vt = vp4[(it < V4) ? it : (V4 - 1)];

    // 3) zero the slice accumulator
    float4* acc4 = reinterpret_cast<float4*>(acc);
    for (int j = tid; j < C4_SUB; j += NTHR)
        acc4[j] = make_float4(0.f, 0.f, 0.f, 0.f);
    __syncthreads();

    // 4) scatter from registers into LDS (filtered to this slice)
    const int lo = sub * C_SUB;
    const int hi = lo + C_SUB;
#pragma unroll
    for (int j = 0; j < NSC; ++j) {
        if (sidx[j] >= lo && sidx[j] < hi) {
            const int i2 = tid + j * NTHR;
            const int a  = (i2 >= 2 * S) ? 2 : (i2 >= S ? 1 : 0);
            atomicAdd(&acc[sidx[j] - lo], cw[a] * sraw[j]);
        }
    }
    __syncthreads();

    // 5) combine + coalesced store stream
#pragma unroll
    for (int k = 0; k < FULL_K; ++k) {
        const int i = i0 + k * NTHR;
        float4 r = acc4[i - base];
        if (i < V4) {
            r.x += coef * v[k].x;  r.y += coef * v[k].y;
            r.z += coef * v[k].z;  r.w += coef * v[k].w;
        }
        out4[i] = r;
    }
    if (has_tail) {
        float4 r = acc4[it - base];
        if (it < V4) {
            r.x += coef * vt.x;  r.y += coef * vt.y;
            r.z += coef * vt.z;  r.w += coef * vt.w;
        }
        out4[it] = r;
    }
}

extern "C" void kernel_launch(void* const* d_in, const int* in_sizes, int n_in,
                              void* d_out, int out_size, void* d_ws, size_t ws_size,
                              hipStream_t stream) {
    const int*   article        = (const int*)  d_in[0]; // [S,B,A]
    const float* vocab_probs    = (const float*)d_in[1]; // [T,B,V]
    const float* gen_probs      = (const float*)d_in[2]; // [T,B,A]
    const float* agentwise_attn = (const float*)d_in[3]; // [T,B,A,S]
    const float* agent_attn     = (const float*)d_in[4]; // [T,B,A]
    float*       out            = (float*)d_out;         // [T,B,V_EXT]

    pg_pipe_kernel<<<dim3(T * B * NSUB), dim3(NTHR), 0, stream>>>(
        article, vocab_probs, gen_probs, agentwise_attn, agent_attn, out);
}

// Round 7
// 37.516 us; speedup vs baseline: 1.8191x; 1.0093x over previous
//
#include <hip/hip_runtime.h>

// Problem dims (fixed by reference)
constexpr int T = 64, B = 8, A = 3, S = 400, V = 50000, N_OOV = 400;
constexpr int V_EXT  = V + N_OOV;      // 50400
constexpr int NSUB   = 6;              // slices per (t,b): 33.6 KB LDS -> 4 blocks/CU
constexpr int C_SUB  = V_EXT / NSUB;   // 8400 floats per slice
constexpr int C4_SUB = C_SUB / 4;      // 2100 float4 per slice
constexpr int V4     = V / 4;          // 12500 float4 of base vocab
constexpr int NTHR   = 512;
constexpr int FULL_K = C4_SUB / NTHR;  // 4 full strides (+52 tail)
constexpr int NSC    = 3;              // ceil(A*S / NTHR) scatter entries/thread

typedef float vfloat4 __attribute__((ext_vector_type(4)));  // builtin-compatible

// One block per (t,b,slice). LDS accumulator for the scatter; fused combine
// stream. Output stores are NON-TEMPORAL (no L2/L3 allocate) so the 103
// MB/replay write stream stops evicting vocab_probs (102.4 MB) from the
// 256 MB Infinity Cache -> steady-state reads become L3 hits, HBM traffic
// ~= writes only.
__global__ __launch_bounds__(NTHR, 8) void pg_nt_kernel(
    const int*   __restrict__ article,        // [S,B,A]
    const float* __restrict__ vocab_probs,    // [T,B,V]
    const float* __restrict__ gen_probs,      // [T,B,A]
    const float* __restrict__ agentwise_attn, // [T,B,A,S]
    const float* __restrict__ agent_attn,     // [T,B,A]
    float*       __restrict__ out)            // [T,B,V_EXT]
{
    __shared__ float acc[C_SUB];               // 33600 B
    const int bid = blockIdx.x;
    const int tb  = bid / NSUB;                // t*B + b
    const int sub = bid - tb * NSUB;
    const int b   = tb % B;
    const int tid = threadIdx.x;

    // per-(t,b) scalars
    float coef = 0.f;
    float cw[A];
#pragma unroll
    for (int a = 0; a < A; ++a) {
        const float aa = agent_attn[tb * A + a];
        const float g  = gen_probs[tb * A + a];
        coef += aa * g;
        cw[a] = aa * (1.f - g);
    }

    // scatter-entry loads (oldest outstanding vmem)
    int   sidx[NSC];
    float sraw[NSC];
    const float* aw = agentwise_attn + (size_t)tb * A * S;   // flat [a*S+s]
#pragma unroll
    for (int j = 0; j < NSC; ++j) {
        const int i2 = tid + j * NTHR;
        sidx[j] = -1; sraw[j] = 0.f;
        if (i2 < A * S) {
            const int a = (i2 >= 2 * S) ? 2 : (i2 >= S ? 1 : 0);
            const int s = i2 - a * S;
            sidx[j] = article[(s * B + b) * A + a];
            sraw[j] = aw[i2];
        }
    }

    // issue vocab reads (normal, cacheable -- we WANT these L3-resident)
    const float4* vp4  = reinterpret_cast<const float4*>(vocab_probs + (size_t)tb * V);
    vfloat4*      out4 = reinterpret_cast<vfloat4*>(out + (size_t)tb * V_EXT);
    const int base = sub * C4_SUB;
    const int i0   = base + tid;

    float4 v[FULL_K];
#pragma unroll
    for (int k = 0; k < FULL_K; ++k) {
        const int i  = i0 + k * NTHR;
        const int ic = (i < V4) ? i : (V4 - 1);   // clamp (only slice 5 mixes)
        v[k] = vp4[ic];
    }
    const int  it       = i0 + FULL_K * NTHR;
    const bool has_tail = (it < base + C4_SUB);   // 52 threads per block
    float4 vt = make_float4(0.f, 0.f, 0.f, 0.f);
    if (has_tail) vt = vp4[(it < V4) ? it : (V4 - 1)];

    // zero the slice accumulator
    float4* acc4 = reinterpret_cast<float4*>(acc);
    for (int j = tid; j < C4_SUB; j += NTHR)
        acc4[j] = make_float4(0.f, 0.f, 0.f, 0.f);
    __syncthreads();

    // scatter from registers into LDS (filtered to this slice)
    const int lo = sub * C_SUB;
    const int hi = lo + C_SUB;
#pragma unroll
    for (int j = 0; j < NSC; ++j) {
        if (sidx[j] >= lo && sidx[j] < hi) {
            const int i2 = tid + j * NTHR;
            const int a  = (i2 >= 2 * S) ? 2 : (i2 >= S ? 1 : 0);
            atomicAdd(&acc[sidx[j] - lo], cw[a] * sraw[j]);
        }
    }
    __syncthreads();

    // combine + NON-TEMPORAL coalesced store stream
#pragma unroll
    for (int k = 0; k < FULL_K; ++k) {
        const int i = i0 + k * NTHR;
        float4 r = acc4[i - base];
        if (i < V4) {
            r.x += coef * v[k].x;  r.y += coef * v[k].y;
            r.z += coef * v[k].z;  r.w += coef * v[k].w;
        }
        vfloat4 rr = {r.x, r.y, r.z, r.w};
        __builtin_nontemporal_store(rr, &out4[i]);
    }
    if (has_tail) {
        float4 r = acc4[it - base];
        if (it < V4) {
            r.x += coef * vt.x;  r.y += coef * vt.y;
            r.z += coef * vt.z;  r.w += coef * vt.w;
        }
        vfloat4 rr = {r.x, r.y, r.z, r.w};
        __builtin_nontemporal_store(rr, &out4[it]);
    }
}

extern "C" void kernel_launch(void* const* d_in, const int* in_sizes, int n_in,
                              void* d_out, int out_size, void* d_ws, size_t ws_size,
                              hipStream_t stream) {
    const int*   article        = (const int*)  d_in[0]; // [S,B,A]
    const float* vocab_probs    = (const float*)d_in[1]; // [T,B,V]
    const float* gen_probs      = (const float*)d_in[2]; // [T,B,A]
    const float* agentwise_attn = (const float*)d_in[3]; // [T,B,A,S]
    const float* agent_attn     = (const float*)d_in[4]; // [T,B,A]
    float*       out            = (float*)d_out;         // [T,B,V_EXT]

    pg_nt_kernel<<<dim3(T * B * NSUB), dim3(NTHR), 0, stream>>>(
        article, vocab_probs, gen_probs, agentwise_attn, agent_attn, out);
}